// Round 3
// baseline (111.743 us; speedup 1.0000x reference)
//
#include <hip/hip_runtime.h>

#define NB   16
#define NC   3
#define NH   512
#define NW   512
#define OUTH 506
#define OUTW 506
#define RPC  6           // output rows per chunk
#define NCHUNK 85        // ceil(506/6)
#define WPB  4           // waves per block (256 threads)
#define NWAVES (NB * NC * NCHUNK)   // 4080

// -------- kernel 0: init workspace (runs every call; harness doesn't re-poison)
__global__ void ssim_init_ws(unsigned int* mn, unsigned int* mx, float* sum) {
    int i = threadIdx.x;
    if (i < NB) { mn[i] = 0x7f7fffffu; mx[i] = 0u; sum[i] = 0.0f; }
}

// -------- kernel 1: per-image min/max of pred (values >= 0 -> uint-bit order == float order)
__global__ __launch_bounds__(256) void ssim_minmax(const float* __restrict__ pred,
                                                   unsigned int* __restrict__ mn,
                                                   unsigned int* __restrict__ mx) {
    int b = blockIdx.y;
    const float4* p4 = (const float4*)(pred + (size_t)b * (NC * NH * NW));
    const int n4 = (NC * NH * NW) / 4;
    float lmin = 3.4e38f, lmax = -3.4e38f;
    for (int i = blockIdx.x * blockDim.x + threadIdx.x; i < n4; i += gridDim.x * blockDim.x) {
        float4 v = p4[i];
        lmin = fminf(lmin, fminf(fminf(v.x, v.y), fminf(v.z, v.w)));
        lmax = fmaxf(lmax, fmaxf(fmaxf(v.x, v.y), fmaxf(v.z, v.w)));
    }
    #pragma unroll
    for (int off = 32; off; off >>= 1) {
        lmin = fminf(lmin, __shfl_down(lmin, off, 64));
        lmax = fmaxf(lmax, __shfl_down(lmax, off, 64));
    }
    __shared__ float smin[4], smax[4];
    int wid = threadIdx.x >> 6, lane = threadIdx.x & 63;
    if (lane == 0) { smin[wid] = lmin; smax[wid] = lmax; }
    __syncthreads();
    if (threadIdx.x == 0) {
        float m = fminf(fminf(smin[0], smin[1]), fminf(smin[2], smin[3]));
        float M = fmaxf(fmaxf(smax[0], smax[1]), fmaxf(smax[2], smax[3]));
        atomicMin(&mn[b], __float_as_uint(m));
        atomicMax(&mx[b], __float_as_uint(M));
    }
}

// -------- kernel 2: register-resident separable sliding-window SSIM
// Each wave: one (image, channel, 6-row chunk), full 512-col width.
// Each lane: exactly 8 cols tracked (40 accumulator VGPRs); the 6-col
// horizontal halo comes from lane+1 via shuffles at emit time only.
__global__ __launch_bounds__(256) void ssim_main(const float* __restrict__ tin,
                                                 const float* __restrict__ pin,
                                                 const unsigned int* __restrict__ mn,
                                                 const unsigned int* __restrict__ mx,
                                                 float* __restrict__ sum) {
    const int wid   = blockIdx.x * WPB + (threadIdx.x >> 6);
    const int lane  = threadIdx.x & 63;
    const int imgch = wid / NCHUNK;
    const int chunk = wid - imgch * NCHUNK;
    const int b     = imgch / NC;
    const int r0    = chunk * RPC;
    const int c0    = lane * 8;

    const float* tb = tin + (size_t)imgch * (NH * NW) + (size_t)r0 * NW + c0;
    const float* pb = pin + (size_t)imgch * (NH * NW) + (size_t)r0 * NW + c0;

    const float dr  = __uint_as_float(mx[b]) - __uint_as_float(mn[b]);
    const float c1  = (0.01f * dr) * (0.01f * dr);
    const float c2  = (0.03f * dr) * (0.03f * dr);
    const float C1s = 2401.0f * c1;   // 49^2 * c1
    const float C2s = 2352.0f * c2;   // 48*49 * c2

    const int nrows = min(RPC, OUTH - r0);   // valid output rows this chunk
    const int kmax  = nrows + 6;             // iterations; emit at k>=6

    float st[8], sp[8], stt[8], spp[8], stp[8];
    #pragma unroll
    for (int i = 0; i < 8; ++i) { st[i]=0.f; sp[i]=0.f; stt[i]=0.f; spp[i]=0.f; stp[i]=0.f; }

    float tA[8], pA[8], tB[8], pB[8];
    float acc = 0.f;

#define LOADROW(DT, DP, ROW) do {                                   \
        const float* _tr = tb + (ROW) * NW;                         \
        const float* _pr = pb + (ROW) * NW;                         \
        *(float4*)&DT[0] = *(const float4*)(_tr);                   \
        *(float4*)&DT[4] = *(const float4*)(_tr + 4);               \
        *(float4*)&DP[0] = *(const float4*)(_pr);                   \
        *(float4*)&DP[4] = *(const float4*)(_pr + 4);               \
    } while (0)

#define SSIMADD(C) do {                                             \
        if (c0 + (C) < OUTW) {                                      \
            float p12 = S1 * S2;                                    \
            float q1  = S1 * S1, q2 = S2 * S2;                      \
            float A1  = fmaf(2.f, p12, C1s);                        \
            float B1  = q1 + q2 + C1s;                              \
            float mtp = fmaf(49.f, S5, -p12);                       \
            float A2  = fmaf(2.f, mtp, C2s);                        \
            float mtt = fmaf(49.f, S3, -q1);                        \
            float mpp = fmaf(49.f, S4, -q2);                        \
            float B2  = mtt + mpp + C2s;                            \
            acc += __fdividef(A1 * A2, B1 * B2);                    \
        }                                                           \
    } while (0)

#define EMIT do {                                                   \
        float h1[6], h2[6], h3[6], h4[6], h5[6];                    \
        _Pragma("unroll")                                           \
        for (int j = 0; j < 6; ++j) {                               \
            h1[j] = __shfl_down(st[j],  1, 64);                     \
            h2[j] = __shfl_down(sp[j],  1, 64);                     \
            h3[j] = __shfl_down(stt[j], 1, 64);                     \
            h4[j] = __shfl_down(spp[j], 1, 64);                     \
            h5[j] = __shfl_down(stp[j], 1, 64);                     \
        }                                                           \
        float S1 = st[0]+st[1]+st[2]+st[3]+st[4]+st[5]+st[6];       \
        float S2 = sp[0]+sp[1]+sp[2]+sp[3]+sp[4]+sp[5]+sp[6];       \
        float S3 = stt[0]+stt[1]+stt[2]+stt[3]+stt[4]+stt[5]+stt[6];\
        float S4 = spp[0]+spp[1]+spp[2]+spp[3]+spp[4]+spp[5]+spp[6];\
        float S5 = stp[0]+stp[1]+stp[2]+stp[3]+stp[4]+stp[5]+stp[6];\
        SSIMADD(0);                                                 \
        _Pragma("unroll")                                           \
        for (int c = 1; c < 8; ++c) {                               \
            S1 += (c == 1 ? st[7]  : h1[c-2]) - st[c-1];            \
            S2 += (c == 1 ? sp[7]  : h2[c-2]) - sp[c-1];            \
            S3 += (c == 1 ? stt[7] : h3[c-2]) - stt[c-1];           \
            S4 += (c == 1 ? spp[7] : h4[c-2]) - spp[c-1];           \
            S5 += (c == 1 ? stp[7] : h5[c-2]) - stp[c-1];           \
            SSIMADD(c);                                             \
        }                                                           \
    } while (0)

#define ITER(K, CT, CP, NT, NP) do {                                \
        float tl[8], pl[8];                                         \
        const bool leave = (K) >= 7;                                \
        if (leave) LOADROW(tl, pl, (K) - 7);                        \
        if ((K) + 1 < kmax) LOADROW(NT, NP, (K) + 1);               \
        _Pragma("unroll")                                           \
        for (int i = 0; i < 8; ++i) {                               \
            float tv = CT[i], pv = CP[i];                           \
            st[i] += tv; sp[i] += pv;                               \
            stt[i] = fmaf(tv, tv, stt[i]);                          \
            spp[i] = fmaf(pv, pv, spp[i]);                          \
            stp[i] = fmaf(tv, pv, stp[i]);                          \
        }                                                           \
        if (leave) {                                                \
            _Pragma("unroll")                                       \
            for (int i = 0; i < 8; ++i) {                           \
                float tv = tl[i], pv = pl[i];                       \
                st[i] -= tv; sp[i] -= pv;                           \
                stt[i] = fmaf(-tv, tv, stt[i]);                     \
                spp[i] = fmaf(-pv, pv, spp[i]);                     \
                stp[i] = fmaf(-tv, pv, stp[i]);                     \
            }                                                       \
        }                                                           \
        if ((K) >= 6) { EMIT; }                                     \
    } while (0)

    LOADROW(tA, pA, 0);
    int k = 0;
    while (true) {
        ITER(k, tA, pA, tB, pB);
        if (++k >= kmax) break;
        ITER(k, tB, pB, tA, pA);
        if (++k >= kmax) break;
    }

#undef ITER
#undef EMIT
#undef SSIMADD
#undef LOADROW

    #pragma unroll
    for (int off = 32; off; off >>= 1) acc += __shfl_down(acc, off, 64);
    if (lane == 0) atomicAdd(&sum[b], acc);
}

// -------- kernel 3: finalize mean
__global__ void ssim_finalize(const float* __restrict__ sum, float* __restrict__ out) {
    int i = threadIdx.x;
    if (i < NB) out[i] = sum[i] / (float)(NC * OUTH * OUTW);
}

extern "C" void kernel_launch(void* const* d_in, const int* in_sizes, int n_in,
                              void* d_out, int out_size, void* d_ws, size_t ws_size,
                              hipStream_t stream) {
    const float* t = (const float*)d_in[0];   // true
    const float* p = (const float*)d_in[1];   // pred
    float* out = (float*)d_out;

    unsigned int* mn  = (unsigned int*)d_ws;
    unsigned int* mx  = mn + NB;
    float*        sum = (float*)(mx + NB);

    ssim_init_ws<<<1, 64, 0, stream>>>(mn, mx, sum);
    ssim_minmax<<<dim3(128, NB), 256, 0, stream>>>(p, mn, mx);

    // 4080 wave-tasks (16 img x 3 ch x 85 row-chunks), 4 waves per block
    ssim_main<<<dim3(NWAVES / WPB), 256, 0, stream>>>(t, p, mn, mx, sum);

    ssim_finalize<<<1, 64, 0, stream>>>(sum, out);
}